// Round 1
// baseline (137.015 us; speedup 1.0000x reference)
//
#include <hip/hip_runtime.h>

// Problem constants (fixed by init_kwargs)
//   key:    [B=2, N=8, T_K=8, K_H=14, K_W=14, C=64]  f32
//   scores: [B=2, N=8, 1568, 1568]                   f32
//   h_emb:  [27, 64], w_emb: [27, 64], t_emb: [15, 64]
//   out:    [B, N, 1568, 1568] f32
//
// rel_h[bn, qh, tk, kh, kw] = dot(h_emb[kh-qh+13, :], key[bn, tk, kh, kw, :])
// rel_w[bn, qw, tk, kh, kw] = dot(w_emb[kw-qw+13, :], key[bn, tk, kh, kw, :])
// rel_t[bn, tq, tk, kh, kw] = dot(t_emb[tk-tq+ 7, :], key[bn, tk, kh, kw, :])
// out[bn, (tq,qh,qw), k] = scores[...] + rel_h[bn,qh,k] + rel_w[bn,qw,k] + rel_t[bn,tq,k]
//   (k = tk*196 + kh*14 + kw is contiguous in all three rel tensors)

#define BN_TOTAL   16        // B*N
#define KLEN       1568      // T_K*K_H*K_W
#define KLEN4      392       // KLEN/4
#define QLEN       1568
#define REL_H_ELEMS (BN_TOTAL * 14 * KLEN)   // 351232
#define REL_T_ELEMS (BN_TOTAL * 8 * KLEN)    // 200704
#define OUT_TOTAL4  (BN_TOTAL * QLEN * KLEN4) // 9,834,496

// MODE: 0 -> coord = kh (bias 13), 1 -> coord = kw (bias 13), 2 -> coord = tk (bias 7)
template <int Q, int MODE>
__global__ void rel_kernel(const float* __restrict__ key,
                           const float* __restrict__ emb,
                           float* __restrict__ rel,
                           int total)
{
    int o = blockIdx.x * blockDim.x + threadIdx.x;
    if (o >= total) return;

    int khw  = o % 196;
    int tmp  = o / 196;          // bn*Q*8 + q*8 + tk
    int tk   = tmp % 8;
    int tmp2 = tmp / 8;          // bn*Q + q
    int q    = tmp2 % Q;
    int bn   = tmp2 / Q;

    int coord;
    if (MODE == 0)      coord = khw / 14;   // kh
    else if (MODE == 1) coord = khw % 14;   // kw
    else                coord = tk;
    int row = coord - q + (Q - 1);          // embedding row

    const float4* kv = (const float4*)(key + (size_t)((bn * 8 + tk) * 196 + khw) * 64);
    const float4* ev = (const float4*)(emb + (size_t)row * 64);

    float acc = 0.f;
#pragma unroll
    for (int c = 0; c < 16; ++c) {
        float4 a = kv[c];
        float4 b = ev[c];
        acc += a.x * b.x + a.y * b.y + a.z * b.z + a.w * b.w;
    }
    rel[o] = acc;
}

__global__ void add_kernel(const float4* __restrict__ scores,
                           const float4* __restrict__ relh,
                           const float4* __restrict__ relw,
                           const float4* __restrict__ relt,
                           float4* __restrict__ out)
{
    int stride = gridDim.x * blockDim.x;
    for (int i = blockIdx.x * blockDim.x + threadIdx.x; i < OUT_TOTAL4; i += stride) {
        int r   = i / KLEN4;           // bn*1568 + q
        int c4  = i - r * KLEN4;       // float4 column within the k-row
        int bn  = r / QLEN;
        int q   = r - bn * QLEN;
        int tq  = q / 196;
        int qhw = q - tq * 196;
        int qh  = qhw / 14;
        int qw  = qhw - qh * 14;

        float4 s = scores[i];
        float4 h = relh[(bn * 14 + qh) * KLEN4 + c4];
        float4 w = relw[(bn * 14 + qw) * KLEN4 + c4];
        float4 t = relt[(bn *  8 + tq) * KLEN4 + c4];

        float4 o;
        o.x = s.x + h.x + w.x + t.x;
        o.y = s.y + h.y + w.y + t.y;
        o.z = s.z + h.z + w.z + t.z;
        o.w = s.w + h.w + w.w + t.w;
        out[i] = o;
    }
}

extern "C" void kernel_launch(void* const* d_in, const int* in_sizes, int n_in,
                              void* d_out, int out_size, void* d_ws, size_t ws_size,
                              hipStream_t stream)
{
    const float* key    = (const float*)d_in[0];
    const float* scores = (const float*)d_in[1];
    const float* hemb   = (const float*)d_in[2];
    const float* wemb   = (const float*)d_in[3];
    const float* temb   = (const float*)d_in[4];
    float*       out    = (float*)d_out;

    // workspace layout: rel_h | rel_w | rel_t
    size_t need = (size_t)(REL_H_ELEMS * 2 + REL_T_ELEMS) * sizeof(float); // ~3.45 MB
    if (ws_size < need) return; // scratch too small (should not happen) -> fail loudly

    float* relh = (float*)d_ws;
    float* relw = relh + REL_H_ELEMS;
    float* relt = relw + REL_H_ELEMS;

    rel_kernel<14, 0><<<REL_H_ELEMS / 256, 256, 0, stream>>>(key, hemb, relh, REL_H_ELEMS);
    rel_kernel<14, 1><<<REL_H_ELEMS / 256, 256, 0, stream>>>(key, wemb, relw, REL_H_ELEMS);
    rel_kernel< 8, 2><<<REL_T_ELEMS / 256, 256, 0, stream>>>(key, temb, relt, REL_T_ELEMS);

    add_kernel<<<2048, 256, 0, stream>>>((const float4*)scores,
                                         (const float4*)relh,
                                         (const float4*)relw,
                                         (const float4*)relt,
                                         (float4*)out);
}

// Round 3
// 90.461 us; speedup vs baseline: 1.5146x; 1.5146x over previous
//
#include <hip/hip_runtime.h>

// Problem constants (fixed by init_kwargs)
//   key:    [B=2, N=8, T_K=8, K_H=14, K_W=14, C=64]  f32
//   scores: [B=2, N=8, 1568, 1568]                   f32
//   h_emb:  [27, 64], w_emb: [27, 64], t_emb: [15, 64]
//   out:    [B, N, 1568, 1568] f32
//
// rel_h[bn, qh, k] = dot(h_emb[kh-qh+13, :], key[bn, k, :])   k = tk*196+kh*14+kw
// rel_w[bn, qw, k] = dot(w_emb[kw-qw+13, :], key[bn, k, :])
// rel_t[bn, tq, k] = dot(t_emb[tk-tq+ 7, :], key[bn, k, :])
// out[bn, (tq,qh,qw), k] = scores + rel_h + rel_w + rel_t

typedef float f4 __attribute__((ext_vector_type(4)));

#define BN_TOTAL    16
#define KLEN        1568
#define KLEN4       392
#define QLEN        1568
#define KV_TOTAL    (BN_TOTAL * KLEN)            // 25088 key vectors
#define REL_H_ELEMS (BN_TOTAL * 14 * KLEN)       // 351232
#define REL_T_ELEMS (BN_TOTAL * 8 * KLEN)        // 200704
#define OUT_TOTAL4  (BN_TOTAL * QLEN * KLEN4)    // 9,834,496 float4 = 9604*1024

#define EROWS  69     // 27 h + 27 w + 15 t
#define EPITCH 68     // 64 + 4 pad floats; 272B row stride (16B aligned)

// One thread per key vector: loads 64 channels into regs once, computes all
// 36 dot products against LDS-staged embedding rows.
__global__ __launch_bounds__(256) void rel_fused(const float* __restrict__ key,
                                                 const float* __restrict__ hemb,
                                                 const float* __restrict__ wemb,
                                                 const float* __restrict__ temb,
                                                 float* __restrict__ relh,
                                                 float* __restrict__ relw,
                                                 float* __restrict__ relt)
{
    __shared__ float se[EROWS * EPITCH];
    for (int idx = threadIdx.x; idx < EROWS * 64; idx += 256) {
        int row = idx >> 6, c = idx & 63;
        float v;
        if (row < 27)      v = hemb[row * 64 + c];
        else if (row < 54) v = wemb[(row - 27) * 64 + c];
        else               v = temb[(row - 54) * 64 + c];
        se[row * EPITCH + c] = v;
    }
    __syncthreads();

    int kv  = blockIdx.x * 256 + threadIdx.x;   // grid is exact: KV_TOTAL/256
    int bn  = kv / KLEN;
    int k   = kv - bn * KLEN;
    int tk  = k / 196;
    int khw = k - tk * 196;
    int kh  = khw / 14;
    int kw  = khw - kh * 14;

    f4 kr[16];
    const f4* kp = (const f4*)(key + (size_t)kv * 64);
#pragma unroll
    for (int c = 0; c < 16; ++c) kr[c] = kp[c];

    // h: rows kh - q + 13, q = 0..13
#pragma unroll
    for (int q = 0; q < 14; ++q) {
        const f4* e = (const f4*)(se + (kh - q + 13) * EPITCH);
        float acc = 0.f;
#pragma unroll
        for (int c = 0; c < 16; ++c) {
            f4 ev = e[c];
            acc += kr[c].x * ev.x + kr[c].y * ev.y + kr[c].z * ev.z + kr[c].w * ev.w;
        }
        relh[(bn * 14 + q) * KLEN + k] = acc;
    }
    // w: rows 27 + kw - q + 13
#pragma unroll
    for (int q = 0; q < 14; ++q) {
        const f4* e = (const f4*)(se + (27 + kw - q + 13) * EPITCH);
        float acc = 0.f;
#pragma unroll
        for (int c = 0; c < 16; ++c) {
            f4 ev = e[c];
            acc += kr[c].x * ev.x + kr[c].y * ev.y + kr[c].z * ev.z + kr[c].w * ev.w;
        }
        relw[(bn * 14 + q) * KLEN + k] = acc;
    }
    // t: rows 54 + tk - q + 7
#pragma unroll
    for (int q = 0; q < 8; ++q) {
        const f4* e = (const f4*)(se + (54 + tk - q + 7) * EPITCH);
        float acc = 0.f;
#pragma unroll
        for (int c = 0; c < 16; ++c) {
            f4 ev = e[c];
            acc += kr[c].x * ev.x + kr[c].y * ev.y + kr[c].z * ev.z + kr[c].w * ev.w;
        }
        relt[(bn * 8 + q) * KLEN + k] = acc;
    }
}

// Exact-grid, 4 float4 per thread (j*256 spacing keeps per-instruction
// coalescing), all 16 loads in flight before the stores.
__global__ __launch_bounds__(256) void add_kernel(const f4* __restrict__ scores,
                                                  const f4* __restrict__ relh,
                                                  const f4* __restrict__ relw,
                                                  const f4* __restrict__ relt,
                                                  f4* __restrict__ out)
{
    int base = blockIdx.x * 1024 + threadIdx.x;

    int idx[4];
    f4  s[4], h[4], w[4], t[4];
#pragma unroll
    for (int j = 0; j < 4; ++j) {
        int i  = base + j * 256;
        idx[j] = i;
        int r   = i / KLEN4;
        int c4  = i - r * KLEN4;
        int bn  = r / QLEN;
        int q   = r - bn * QLEN;
        int tq  = q / 196;
        int qhw = q - tq * 196;
        int qh  = qhw / 14;
        int qw  = qhw - qh * 14;

        s[j] = __builtin_nontemporal_load(scores + i);
        h[j] = relh[(bn * 14 + qh) * KLEN4 + c4];
        w[j] = relw[(bn * 14 + qw) * KLEN4 + c4];
        t[j] = relt[(bn *  8 + tq) * KLEN4 + c4];
    }
#pragma unroll
    for (int j = 0; j < 4; ++j) {
        f4 o = s[j] + h[j] + w[j] + t[j];
        __builtin_nontemporal_store(o, out + idx[j]);
    }
}

extern "C" void kernel_launch(void* const* d_in, const int* in_sizes, int n_in,
                              void* d_out, int out_size, void* d_ws, size_t ws_size,
                              hipStream_t stream)
{
    const float* key    = (const float*)d_in[0];
    const float* scores = (const float*)d_in[1];
    const float* hemb   = (const float*)d_in[2];
    const float* wemb   = (const float*)d_in[3];
    const float* temb   = (const float*)d_in[4];
    float*       out    = (float*)d_out;

    size_t need = (size_t)(REL_H_ELEMS * 2 + REL_T_ELEMS) * sizeof(float); // ~3.45 MB
    if (ws_size < need) return;

    float* relh = (float*)d_ws;
    float* relw = relh + REL_H_ELEMS;
    float* relt = relw + REL_H_ELEMS;

    rel_fused<<<KV_TOTAL / 256, 256, 0, stream>>>(key, hemb, wemb, temb, relh, relw, relt);

    add_kernel<<<OUT_TOTAL4 / 1024, 256, 0, stream>>>((const f4*)scores,
                                                      (const f4*)relh,
                                                      (const f4*)relw,
                                                      (const f4*)relt,
                                                      (f4*)out);
}